// Round 11
// baseline (89.343 us; speedup 1.0000x reference)
//
#include <hip/hip_runtime.h>

#define NB 8192
#define ND 128
#define NC 1000
#define NJC 16    // j-chunks
#define JCB 4     // j-blocks per chunk
#define JBS 128   // j-rows per j-block
#define NIS 32    // i-slices (256 i each)
#define CAP 64    // bucket capacity per class
#define NRB (NB / 4)  // reduce blocks = 2048

typedef __attribute__((ext_vector_type(8))) short bf16x8;
typedef __attribute__((ext_vector_type(4))) float f32x4;

__device__ __forceinline__ unsigned short f2bf(float f) {
    unsigned int u = __float_as_uint(f);
    return (unsigned short)((u + 0x7fffu + ((u >> 16) & 1u)) >> 16);
}

// ---------------- CE (label smoothing) fused with emb->bf16 conversion + cnt zeroing ---------
__global__ __launch_bounds__(256) void ce_prep_kernel(const float* __restrict__ logits,
                                                      const float* __restrict__ emb,
                                                      const int* __restrict__ labels,
                                                      unsigned short* __restrict__ ebf,
                                                      float* __restrict__ cls_part,
                                                      int* __restrict__ cnt) {
    int wave = threadIdx.x >> 6, lane = threadIdx.x & 63;
    int r = blockIdx.x * 4 + wave;

    if (blockIdx.x == 0) {
        for (int k = threadIdx.x; k < NC; k += 256) cnt[k] = 0;
    }

    {
        const float* erow = emb + (size_t)r * ND;
        float2 v = *(const float2*)(erow + lane * 2);
        unsigned int packed = (unsigned int)f2bf(v.x) | ((unsigned int)f2bf(v.y) << 16);
        *(unsigned int*)(ebf + (size_t)r * ND + lane * 2) = packed;
    }

    const float* x = logits + (size_t)r * NC;
    float4 q0 = *(const float4*)(x + 4 * lane);
    float4 q1 = *(const float4*)(x + 256 + 4 * lane);
    float4 q2 = *(const float4*)(x + 512 + 4 * lane);
    float4 q3;
    bool a3 = (192 + lane) < 250;
    if (a3) q3 = *(const float4*)(x + 768 + 4 * lane);
    else q3 = make_float4(-3.4e38f, -3.4e38f, -3.4e38f, -3.4e38f);

    float m = fmaxf(fmaxf(fmaxf(q0.x, q0.y), fmaxf(q0.z, q0.w)),
                    fmaxf(fmaxf(q1.x, q1.y), fmaxf(q1.z, q1.w)));
    m = fmaxf(m, fmaxf(fmaxf(q2.x, q2.y), fmaxf(q2.z, q2.w)));
    m = fmaxf(m, fmaxf(fmaxf(q3.x, q3.y), fmaxf(q3.z, q3.w)));
    float s = (q0.x + q0.y + q0.z + q0.w) + (q1.x + q1.y + q1.z + q1.w) +
              (q2.x + q2.y + q2.z + q2.w) +
              (a3 ? (q3.x + q3.y + q3.z + q3.w) : 0.f);
#pragma unroll
    for (int o = 32; o >= 1; o >>= 1) {
        m = fmaxf(m, __shfl_xor(m, o));
        s += __shfl_xor(s, o);
    }
    float se = expf(q0.x - m) + expf(q0.y - m) + expf(q0.z - m) + expf(q0.w - m) +
               expf(q1.x - m) + expf(q1.y - m) + expf(q1.z - m) + expf(q1.w - m) +
               expf(q2.x - m) + expf(q2.y - m) + expf(q2.z - m) + expf(q2.w - m) +
               expf(q3.x - m) + expf(q3.y - m) + expf(q3.z - m) + expf(q3.w - m);
#pragma unroll
    for (int o = 32; o >= 1; o >>= 1) se += __shfl_xor(se, o);
    float xl = x[labels[r]];
    float v = (m + logf(se)) - 0.9f * xl - 0.1f * (s * (1.0f / NC));
    if (lane == 0) cls_part[r] = v;
}

// ---------------- bucket: per-class row lists; also zeroes the done counter ----------------
__global__ __launch_bounds__(256) void bucket_kernel(const int* __restrict__ labels,
                                                     int* __restrict__ cnt,
                                                     int* __restrict__ lists,
                                                     int* __restrict__ done) {
    if (blockIdx.x == 0 && threadIdx.x == 0) done[0] = 0;
    int r = blockIdx.x * 256 + threadIdx.x;
    int c = labels[r];
    int slot = atomicAdd(&cnt[c], 1);
    if (slot < CAP) lists[c * CAP + slot] = r;
}

// ---------------- mining: j-chunked, double-buffered LDS; A-frags amortized over 4 j-blocks --
// grid (NJC, NIS) = 512 blocks; block keeps 256 i-rows' A-frags in registers, sweeps 512 j.
__global__ __launch_bounds__(256, 2) void mine_kernel(const unsigned short* __restrict__ ebf,
                                                      const int* __restrict__ labels,
                                                      float* __restrict__ part) {
    __shared__ unsigned short btile[2][JBS * ND];  // 2 x 32 KB
    int tid = threadIdx.x;
    int wave = tid >> 6, lane = tid & 63;
    int col = lane & 15, grp = lane >> 4;
    int jchunk = blockIdx.x, jcbase = jchunk * (JCB * JBS);
    int ibase = blockIdx.y * 256 + wave * 64;

    // stage one 128-row j-block: XOR-swizzled global source -> linear LDS dest (rule #21)
#define STAGE(buf, jb0)                                                                \
    do {                                                                               \
        _Pragma("unroll")                                                              \
        for (int rep = 0; rep < 8; ++rep) {                                            \
            int row = (tid >> 4) + rep * 16;                                           \
            const unsigned short* src =                                                \
                ebf + (size_t)((jb0) + row) * ND + (((tid & 15) ^ (row & 7)) << 3);    \
            unsigned short* dst = &btile[buf][0] + (size_t)(wave * 4 + rep * 16) * ND; \
            __builtin_amdgcn_global_load_lds(                                          \
                (const __attribute__((address_space(1))) unsigned int*)src,            \
                (__attribute__((address_space(3))) unsigned int*)dst, 16, 0, 0);       \
        }                                                                              \
    } while (0)

    STAGE(0, jcbase);  // j-block 0 in flight

    // A fragments: 4 i-chunks x 4 k-chunks, registers for whole kernel
    bf16x8 af[4][4];
#pragma unroll
    for (int ic = 0; ic < 4; ++ic) {
        const unsigned short* ap = ebf + (size_t)(ibase + ic * 16 + col) * ND + (grp << 3);
#pragma unroll
        for (int kc = 0; kc < 4; ++kc) af[ic][kc] = *(const bf16x8*)(ap + kc * 32);
    }
    int li[16];
#pragma unroll
    for (int ic = 0; ic < 4; ++ic)
#pragma unroll
        for (int r = 0; r < 4; ++r) li[ic * 4 + r] = labels[ibase + ic * 16 + grp * 4 + r];
    // all 32 j-labels this lane needs (8 sub-tiles x 4 j-blocks), loaded once
    int ljall[JCB * 8];
#pragma unroll
    for (int jb = 0; jb < JCB; ++jb)
#pragma unroll
        for (int st = 0; st < 8; ++st)
            ljall[jb * 8 + st] = labels[jcbase + jb * JBS + st * 16 + col];

    float bn[16];
#pragma unroll
    for (int k = 0; k < 16; ++k) bn[k] = -3.4e38f;

    __syncthreads();  // drains stage(0) + A/label loads; btile[0] published

#pragma unroll
    for (int t = 0; t < JCB; ++t) {
        if (t + 1 < JCB) STAGE((t + 1) & 1, jcbase + (t + 1) * JBS);  // prefetch next

        const unsigned short* bt = &btile[t & 1][0];
#pragma unroll
        for (int st = 0; st < 8; ++st) {
            bf16x8 bfr[4];
#pragma unroll
            for (int kc = 0; kc < 4; ++kc) {
                int chunk = (grp + 4 * kc) ^ (col & 7);
                bfr[kc] = *(const bf16x8*)(bt + (size_t)(st * 16 + col) * ND + chunk * 8);
            }
            f32x4 acc[4] = {{0.f, 0.f, 0.f, 0.f}, {0.f, 0.f, 0.f, 0.f},
                            {0.f, 0.f, 0.f, 0.f}, {0.f, 0.f, 0.f, 0.f}};
#pragma unroll
            for (int kc = 0; kc < 4; ++kc)
#pragma unroll
                for (int ic = 0; ic < 4; ++ic)
                    acc[ic] = __builtin_amdgcn_mfma_f32_16x16x32_bf16(af[ic][kc], bfr[kc],
                                                                      acc[ic], 0, 0, 0);
            int lj = ljall[t * 8 + st];
#pragma unroll
            for (int ic = 0; ic < 4; ++ic)
#pragma unroll
                for (int r = 0; r < 4; ++r)
                    bn[ic * 4 + r] =
                        fmaxf(bn[ic * 4 + r], (lj == li[ic * 4 + r]) ? -3.4e38f : acc[ic][r]);
        }

        if (t + 1 < JCB) __syncthreads();  // drain my stage(t+1) (vmcnt0), publish buffer
    }
#undef STAGE

    // max over the 16 columns (lanes sharing grp); one value per row per j-chunk
#pragma unroll
    for (int k = 0; k < 16; ++k)
#pragma unroll
        for (int msk = 1; msk <= 8; msk <<= 1)
            bn[k] = fmaxf(bn[k], __shfl_xor(bn[k], msk));
    if (col == 0) {
#pragma unroll
        for (int ic = 0; ic < 4; ++ic)
#pragma unroll
            for (int r = 0; r < 4; ++r) {
                int gi = ibase + ic * 16 + grp * 4 + r;
                part[((size_t)gi << 4) + jchunk] = bn[ic * 4 + r];
            }
    }
}

// ---------------- reduce + final combine (last-block-done) ----------------
// one wave per row; per-block partials -> blk[]; last finished block sums in fixed order.
__global__ __launch_bounds__(256) void reduce_fin_kernel(const float* __restrict__ e,
                                                         const int* __restrict__ labels,
                                                         const float* __restrict__ part,
                                                         const int* __restrict__ cnt,
                                                         const int* __restrict__ lists,
                                                         const float* __restrict__ cls_part,
                                                         float4* __restrict__ blk,
                                                         int* __restrict__ done,
                                                         float* __restrict__ out) {
    __shared__ float sp[4], sv[4], sc[4];
    __shared__ int isLast;
    int wave = threadIdx.x >> 6, lane = threadIdx.x & 63;
    int r = blockIdx.x * 4 + wave;

    // merge 16 neg partials (value-only max)
    float nb = part[((size_t)r << 4) + (lane & 15)];
#pragma unroll
    for (int o = 1; o <= 8; o <<= 1) nb = fmaxf(nb, __shfl_xor(nb, o));
    float d_an = sqrtf(fmaxf(2.0f - 2.0f * nb, 0.0f));

    int myl = labels[r];
    int ctot = cnt[myl];
    int n = min(ctot, CAP);
    const float* a = e + (size_t)r * ND;
    float2 av = *(const float2*)(a + lane * 2);

    // exact fp32 argmax over same-class candidates; (d2, smaller-j) tie-break
    float best = -1.0f;
    int jp = r;
    for (int k = 0; k < n; ++k) {
        int j2 = lists[myl * CAP + k];  // wave-uniform
        if (j2 == r) continue;
        const float* p = e + (size_t)j2 * ND;
        float2 pv = *(const float2*)(p + lane * 2);
        float dx = av.x - pv.x, dy = av.y - pv.y;
        float ss = dx * dx + dy * dy;
#pragma unroll
        for (int o = 32; o >= 1; o >>= 1) ss += __shfl_xor(ss, o);
        if (ss > best || (ss == best && j2 < jp)) { best = ss; jp = j2; }
    }
    bool valid = (ctot >= 2) && (ctot < NB);

    // winner recomputed with torch's +eps inside the norm
    const float* p = e + (size_t)jp * ND;
    float2 pv = *(const float2*)(p + lane * 2);
    float dx = av.x - pv.x + 1e-6f, dy = av.y - pv.y + 1e-6f;
    float ss = dx * dx + dy * dy;
#pragma unroll
    for (int o = 32; o >= 1; o >>= 1) ss += __shfl_xor(ss, o);
    float d_ap = sqrtf(ss);

    if (lane == 0) {
        sp[wave] = valid ? fmaxf(d_ap - d_an + 0.5f, 0.0f) : 0.0f;
        sv[wave] = valid ? 1.0f : 0.0f;
        sc[wave] = cls_part[r];
    }
    __syncthreads();
    if (threadIdx.x == 0) {
        blk[blockIdx.x] = make_float4(sp[0] + sp[1] + sp[2] + sp[3],
                                      sv[0] + sv[1] + sv[2] + sv[3],
                                      sc[0] + sc[1] + sc[2] + sc[3], 0.f);
        __threadfence();
        int old = atomicAdd(done, 1);
        isLast = (old == NRB - 1) ? 1 : 0;
    }
    __syncthreads();

    if (isLast) {
        __threadfence();  // ensure all blk[] writes are observed
        float P = 0.f, V = 0.f, C = 0.f;
        for (int k = threadIdx.x; k < NRB; k += 256) {
            float4 q = blk[k];
            P += q.x;
            V += q.y;
            C += q.z;
        }
#pragma unroll
        for (int o = 32; o >= 1; o >>= 1) {
            P += __shfl_xor(P, o);
            V += __shfl_xor(V, o);
            C += __shfl_xor(C, o);
        }
        __syncthreads();  // sp/sv/sc reuse
        if (lane == 0) { sp[wave] = P; sv[wave] = V; sc[wave] = C; }
        __syncthreads();
        if (threadIdx.x == 0) {
            float Pt = sp[0] + sp[1] + sp[2] + sp[3];
            float Vt = sv[0] + sv[1] + sv[2] + sv[3];
            float Ct = sc[0] + sc[1] + sc[2] + sc[3];
            float tri = Vt > 0.5f ? Pt / Vt : 0.0f;
            out[0] = Ct * (1.0f / NB) + tri;
        }
    }
}

extern "C" void kernel_launch(void* const* d_in, const int* in_sizes, int n_in,
                              void* d_out, int out_size, void* d_ws, size_t ws_size,
                              hipStream_t stream) {
    const float* logits = (const float*)d_in[0];
    const float* emb = (const float*)d_in[1];
    const int* labels = (const int*)d_in[2];

    char* w = (char*)d_ws;
    unsigned short* ebf = (unsigned short*)w;                 // 2 MB
    float* part = (float*)(w + 2097152);                      // NB*16 f32 (512 KB)
    float* cls_part = (float*)(w + 2621440);                  // NB f32 (32 KB)
    int* cnt = (int*)(w + 2654208);                           // NC int (4 KB)
    int* lists = (int*)(w + 2658304);                         // NC*CAP int (256 KB)
    float4* blk = (float4*)(w + 2920448);                     // NRB float4 (32 KB)
    int* done = (int*)(w + 2953216);                          // 1 int

    ce_prep_kernel<<<NB / 4, 256, 0, stream>>>(logits, emb, labels, ebf, cls_part, cnt);
    bucket_kernel<<<NB / 256, 256, 0, stream>>>(labels, cnt, lists, done);
    mine_kernel<<<dim3(NJC, NIS), 256, 0, stream>>>(ebf, labels, part);
    reduce_fin_kernel<<<NRB, 256, 0, stream>>>(emb, labels, part, cnt, lists, cls_part,
                                               blk, done, (float*)d_out);
}

// Round 12
// 50.967 us; speedup vs baseline: 1.7530x; 1.7530x over previous
//
#include <hip/hip_runtime.h>

#define NB 8192
#define ND 128
#define NC 1000
#define NJC 16    // j-chunks
#define JCB 4     // j-blocks per chunk
#define JBS 128   // j-rows per j-block
#define NIS 32    // i-slices (256 i each)
#define CAP 64    // bucket capacity per class

typedef __attribute__((ext_vector_type(8))) short bf16x8;
typedef __attribute__((ext_vector_type(4))) float f32x4;

__device__ __forceinline__ unsigned short f2bf(float f) {
    unsigned int u = __float_as_uint(f);
    return (unsigned short)((u + 0x7fffu + ((u >> 16) & 1u)) >> 16);
}

// ---------------- CE (label smoothing) fused with emb->bf16 conversion + cnt zeroing ---------
__global__ __launch_bounds__(256) void ce_prep_kernel(const float* __restrict__ logits,
                                                      const float* __restrict__ emb,
                                                      const int* __restrict__ labels,
                                                      unsigned short* __restrict__ ebf,
                                                      float* __restrict__ cls_part,
                                                      int* __restrict__ cnt) {
    int wave = threadIdx.x >> 6, lane = threadIdx.x & 63;
    int r = blockIdx.x * 4 + wave;

    if (blockIdx.x == 0) {
        for (int k = threadIdx.x; k < NC; k += 256) cnt[k] = 0;
    }

    {
        const float* erow = emb + (size_t)r * ND;
        float2 v = *(const float2*)(erow + lane * 2);
        unsigned int packed = (unsigned int)f2bf(v.x) | ((unsigned int)f2bf(v.y) << 16);
        *(unsigned int*)(ebf + (size_t)r * ND + lane * 2) = packed;
    }

    const float* x = logits + (size_t)r * NC;
    float4 q0 = *(const float4*)(x + 4 * lane);
    float4 q1 = *(const float4*)(x + 256 + 4 * lane);
    float4 q2 = *(const float4*)(x + 512 + 4 * lane);
    float4 q3;
    bool a3 = (192 + lane) < 250;
    if (a3) q3 = *(const float4*)(x + 768 + 4 * lane);
    else q3 = make_float4(-3.4e38f, -3.4e38f, -3.4e38f, -3.4e38f);

    float m = fmaxf(fmaxf(fmaxf(q0.x, q0.y), fmaxf(q0.z, q0.w)),
                    fmaxf(fmaxf(q1.x, q1.y), fmaxf(q1.z, q1.w)));
    m = fmaxf(m, fmaxf(fmaxf(q2.x, q2.y), fmaxf(q2.z, q2.w)));
    m = fmaxf(m, fmaxf(fmaxf(q3.x, q3.y), fmaxf(q3.z, q3.w)));
    float s = (q0.x + q0.y + q0.z + q0.w) + (q1.x + q1.y + q1.z + q1.w) +
              (q2.x + q2.y + q2.z + q2.w) +
              (a3 ? (q3.x + q3.y + q3.z + q3.w) : 0.f);
#pragma unroll
    for (int o = 32; o >= 1; o >>= 1) {
        m = fmaxf(m, __shfl_xor(m, o));
        s += __shfl_xor(s, o);
    }
    float se = expf(q0.x - m) + expf(q0.y - m) + expf(q0.z - m) + expf(q0.w - m) +
               expf(q1.x - m) + expf(q1.y - m) + expf(q1.z - m) + expf(q1.w - m) +
               expf(q2.x - m) + expf(q2.y - m) + expf(q2.z - m) + expf(q2.w - m) +
               expf(q3.x - m) + expf(q3.y - m) + expf(q3.z - m) + expf(q3.w - m);
#pragma unroll
    for (int o = 32; o >= 1; o >>= 1) se += __shfl_xor(se, o);
    float xl = x[labels[r]];
    float v = (m + logf(se)) - 0.9f * xl - 0.1f * (s * (1.0f / NC));
    if (lane == 0) cls_part[r] = v;
}

// ---------------- bucket: per-class row lists (order nondeterministic, consumers tie-break) ---
__global__ __launch_bounds__(256) void bucket_kernel(const int* __restrict__ labels,
                                                     int* __restrict__ cnt,
                                                     int* __restrict__ lists) {
    int r = blockIdx.x * 256 + threadIdx.x;
    int c = labels[r];
    int slot = atomicAdd(&cnt[c], 1);
    if (slot < CAP) lists[c * CAP + slot] = r;
}

// ---------------- mining: j-chunked, double-buffered LDS; A-frags amortized over 4 j-blocks --
__global__ __launch_bounds__(256, 2) void mine_kernel(const unsigned short* __restrict__ ebf,
                                                      const int* __restrict__ labels,
                                                      float* __restrict__ part) {
    __shared__ unsigned short btile[2][JBS * ND];  // 2 x 32 KB
    int tid = threadIdx.x;
    int wave = tid >> 6, lane = tid & 63;
    int col = lane & 15, grp = lane >> 4;
    int jchunk = blockIdx.x, jcbase = jchunk * (JCB * JBS);
    int ibase = blockIdx.y * 256 + wave * 64;

#define STAGE(buf, jb0)                                                                \
    do {                                                                               \
        _Pragma("unroll")                                                              \
        for (int rep = 0; rep < 8; ++rep) {                                            \
            int row = (tid >> 4) + rep * 16;                                           \
            const unsigned short* src =                                                \
                ebf + (size_t)((jb0) + row) * ND + (((tid & 15) ^ (row & 7)) << 3);    \
            unsigned short* dst = &btile[buf][0] + (size_t)(wave * 4 + rep * 16) * ND; \
            __builtin_amdgcn_global_load_lds(                                          \
                (const __attribute__((address_space(1))) unsigned int*)src,            \
                (__attribute__((address_space(3))) unsigned int*)dst, 16, 0, 0);       \
        }                                                                              \
    } while (0)

    STAGE(0, jcbase);

    bf16x8 af[4][4];
#pragma unroll
    for (int ic = 0; ic < 4; ++ic) {
        const unsigned short* ap = ebf + (size_t)(ibase + ic * 16 + col) * ND + (grp << 3);
#pragma unroll
        for (int kc = 0; kc < 4; ++kc) af[ic][kc] = *(const bf16x8*)(ap + kc * 32);
    }
    int li[16];
#pragma unroll
    for (int ic = 0; ic < 4; ++ic)
#pragma unroll
        for (int r = 0; r < 4; ++r) li[ic * 4 + r] = labels[ibase + ic * 16 + grp * 4 + r];
    int ljall[JCB * 8];
#pragma unroll
    for (int jb = 0; jb < JCB; ++jb)
#pragma unroll
        for (int st = 0; st < 8; ++st)
            ljall[jb * 8 + st] = labels[jcbase + jb * JBS + st * 16 + col];

    float bn[16];
#pragma unroll
    for (int k = 0; k < 16; ++k) bn[k] = -3.4e38f;

    __syncthreads();  // drains stage(0) + A/label loads

#pragma unroll
    for (int t = 0; t < JCB; ++t) {
        if (t + 1 < JCB) STAGE((t + 1) & 1, jcbase + (t + 1) * JBS);

        const unsigned short* bt = &btile[t & 1][0];
#pragma unroll
        for (int st = 0; st < 8; ++st) {
            bf16x8 bfr[4];
#pragma unroll
            for (int kc = 0; kc < 4; ++kc) {
                int chunk = (grp + 4 * kc) ^ (col & 7);
                bfr[kc] = *(const bf16x8*)(bt + (size_t)(st * 16 + col) * ND + chunk * 8);
            }
            f32x4 acc[4] = {{0.f, 0.f, 0.f, 0.f}, {0.f, 0.f, 0.f, 0.f},
                            {0.f, 0.f, 0.f, 0.f}, {0.f, 0.f, 0.f, 0.f}};
#pragma unroll
            for (int kc = 0; kc < 4; ++kc)
#pragma unroll
                for (int ic = 0; ic < 4; ++ic)
                    acc[ic] = __builtin_amdgcn_mfma_f32_16x16x32_bf16(af[ic][kc], bfr[kc],
                                                                      acc[ic], 0, 0, 0);
            int lj = ljall[t * 8 + st];
#pragma unroll
            for (int ic = 0; ic < 4; ++ic)
#pragma unroll
                for (int r = 0; r < 4; ++r)
                    bn[ic * 4 + r] =
                        fmaxf(bn[ic * 4 + r], (lj == li[ic * 4 + r]) ? -3.4e38f : acc[ic][r]);
        }

        if (t + 1 < JCB) __syncthreads();
    }
#undef STAGE

#pragma unroll
    for (int k = 0; k < 16; ++k)
#pragma unroll
        for (int msk = 1; msk <= 8; msk <<= 1)
            bn[k] = fmaxf(bn[k], __shfl_xor(bn[k], msk));
    if (col == 0) {
#pragma unroll
        for (int ic = 0; ic < 4; ++ic)
#pragma unroll
            for (int r = 0; r < 4; ++r) {
                int gi = ibase + ic * 16 + grp * 4 + r;
                part[((size_t)gi << 4) + jchunk] = bn[ic * 4 + r];
            }
    }
}

// ---------------- reduce: neg from mined value; pos via PARALLEL candidate scan ----------------
// one wave per row; 8 lane-groups of 8 handle 8 candidates simultaneously (16 floats/lane),
// 3-shuffle group reduce + 3-shuffle cross-group argmax with (d2, smaller-j) tie-break.
__global__ __launch_bounds__(256) void reduce_kernel(const float* __restrict__ e,
                                                     const int* __restrict__ labels,
                                                     const float* __restrict__ part,
                                                     const int* __restrict__ cnt,
                                                     const int* __restrict__ lists,
                                                     float2* __restrict__ tri_part) {
    int wave = threadIdx.x >> 6, lane = threadIdx.x & 63;
    int r = blockIdx.x * 4 + wave;
    int g = lane >> 3, sl = lane & 7;

    // merge 16 neg partials (value-only max)
    float nb = part[((size_t)r << 4) + (lane & 15)];
#pragma unroll
    for (int o = 1; o <= 8; o <<= 1) nb = fmaxf(nb, __shfl_xor(nb, o));
    float d_an = sqrtf(fmaxf(2.0f - 2.0f * nb, 0.0f));

    int myl = labels[r];
    int ctot = cnt[myl];
    int n = min(ctot, CAP);
    const float* a = e + (size_t)r * ND;

    // my 16-float segment of row r
    float4 a0 = *(const float4*)(a + sl * 16);
    float4 a1 = *(const float4*)(a + sl * 16 + 4);
    float4 a2 = *(const float4*)(a + sl * 16 + 8);
    float4 a3 = *(const float4*)(a + sl * 16 + 12);

    float best = -1.0f;
    int jp = r;
    for (int base = 0; base < n; base += 8) {
        int idx = base + g;
        bool ok = (idx < n);
        int j2 = ok ? lists[myl * CAP + idx] : r;
        const float* p = e + (size_t)j2 * ND;
        float4 p0 = *(const float4*)(p + sl * 16);
        float4 p1 = *(const float4*)(p + sl * 16 + 4);
        float4 p2 = *(const float4*)(p + sl * 16 + 8);
        float4 p3 = *(const float4*)(p + sl * 16 + 12);
        float d, ss = 0.f;
        d = a0.x - p0.x; ss += d * d; d = a0.y - p0.y; ss += d * d;
        d = a0.z - p0.z; ss += d * d; d = a0.w - p0.w; ss += d * d;
        d = a1.x - p1.x; ss += d * d; d = a1.y - p1.y; ss += d * d;
        d = a1.z - p1.z; ss += d * d; d = a1.w - p1.w; ss += d * d;
        d = a2.x - p2.x; ss += d * d; d = a2.y - p2.y; ss += d * d;
        d = a2.z - p2.z; ss += d * d; d = a2.w - p2.w; ss += d * d;
        d = a3.x - p3.x; ss += d * d; d = a3.y - p3.y; ss += d * d;
        d = a3.z - p3.z; ss += d * d; d = a3.w - p3.w; ss += d * d;
        ss += __shfl_xor(ss, 1);
        ss += __shfl_xor(ss, 2);
        ss += __shfl_xor(ss, 4);  // group-uniform d2
        float d2v = (ok && j2 != r) ? ss : -2.0f;
        if (d2v > best || (d2v == best && j2 < jp)) { best = d2v; jp = j2; }
    }
    // cross-group argmax (tie -> smaller j); makes (best, jp) wave-uniform
#pragma unroll
    for (int msk = 8; msk <= 32; msk <<= 1) {
        float ob = __shfl_xor(best, msk);
        int oj = __shfl_xor(jp, msk);
        if (ob > best || (ob == best && oj < jp)) { best = ob; jp = oj; }
    }
    bool valid = (ctot >= 2) && (ctot < NB);

    // winner recomputed with torch's +eps inside the norm (jp==r when none: unused)
    const float* p = e + (size_t)jp * ND;
    float2 av = *(const float2*)(a + lane * 2);
    float2 pv = *(const float2*)(p + lane * 2);
    float dx = av.x - pv.x + 1e-6f, dy = av.y - pv.y + 1e-6f;
    float ss = dx * dx + dy * dy;
#pragma unroll
    for (int o = 32; o >= 1; o >>= 1) ss += __shfl_xor(ss, o);
    float d_ap = sqrtf(ss);

    if (lane == 0) {
        float per = valid ? fmaxf(d_ap - d_an + 0.5f, 0.0f) : 0.0f;
        tri_part[r] = make_float2(per, valid ? 1.0f : 0.0f);
    }
}

// ---------------- final combine: single block tree-reduces all partials ----------------
__global__ __launch_bounds__(1024) void fin_kernel(const float* __restrict__ cls_part,
                                                   const float2* __restrict__ tri_part,
                                                   float* __restrict__ out) {
    __shared__ float sc[16], sp[16], sn[16];
    int t = threadIdx.x;
    int wave = t >> 6, lane = t & 63;
    float c = 0.f, tp = 0.f, tc = 0.f;
    for (int k = t; k < NB; k += 1024) {
        c += cls_part[k];
        float2 q = tri_part[k];
        tp += q.x;
        tc += q.y;
    }
#pragma unroll
    for (int o = 32; o >= 1; o >>= 1) {
        c += __shfl_xor(c, o);
        tp += __shfl_xor(tp, o);
        tc += __shfl_xor(tc, o);
    }
    if (lane == 0) { sc[wave] = c; sp[wave] = tp; sn[wave] = tc; }
    __syncthreads();
    if (t == 0) {
        float C = 0.f, P = 0.f, V = 0.f;
        for (int w = 0; w < 16; ++w) { C += sc[w]; P += sp[w]; V += sn[w]; }
        float cls = C * (1.0f / NB);
        float tri = V > 0.5f ? P / V : 0.0f;
        out[0] = cls + tri;
    }
}

extern "C" void kernel_launch(void* const* d_in, const int* in_sizes, int n_in,
                              void* d_out, int out_size, void* d_ws, size_t ws_size,
                              hipStream_t stream) {
    const float* logits = (const float*)d_in[0];
    const float* emb = (const float*)d_in[1];
    const int* labels = (const int*)d_in[2];

    char* w = (char*)d_ws;
    unsigned short* ebf = (unsigned short*)w;                 // 2 MB
    float* part = (float*)(w + 2097152);                      // NB*16 f32 (512 KB)
    float* cls_part = (float*)(w + 2621440);                  // NB f32 (32 KB)
    float2* tri_part = (float2*)(w + 2654208);                // NB f32x2 (64 KB)
    int* cnt = (int*)(w + 2719744);                           // NC int (4 KB)
    int* lists = (int*)(w + 2723840);                         // NC*CAP int (256 KB)

    ce_prep_kernel<<<NB / 4, 256, 0, stream>>>(logits, emb, labels, ebf, cls_part, cnt);
    bucket_kernel<<<NB / 256, 256, 0, stream>>>(labels, cnt, lists);
    mine_kernel<<<dim3(NJC, NIS), 256, 0, stream>>>(ebf, labels, part);
    reduce_kernel<<<NB / 4, 256, 0, stream>>>(emb, labels, part, cnt, lists, tri_part);
    fin_kernel<<<1, 1024, 0, stream>>>(cls_part, tri_part, (float*)d_out);
}

// Round 13
// 50.407 us; speedup vs baseline: 1.7724x; 1.0111x over previous
//
#include <hip/hip_runtime.h>

#define NB 8192
#define ND 128
#define NC 1000
#define NJC 16    // j-chunks
#define JCB 4     // j-blocks per chunk
#define JBS 128   // j-rows per j-block
#define NIS 16    // i-slices (512 i each)
#define CAP 64    // bucket capacity per class
#define NRB (NB / 4)  // reduce blocks

typedef __attribute__((ext_vector_type(8))) short bf16x8;
typedef __attribute__((ext_vector_type(4))) float f32x4;

__device__ __forceinline__ unsigned short f2bf(float f) {
    unsigned int u = __float_as_uint(f);
    return (unsigned short)((u + 0x7fffu + ((u >> 16) & 1u)) >> 16);
}

// ---------------- CE (label smoothing) fused with emb->bf16 conversion + cnt zeroing ---------
__global__ __launch_bounds__(256) void ce_prep_kernel(const float* __restrict__ logits,
                                                      const float* __restrict__ emb,
                                                      const int* __restrict__ labels,
                                                      unsigned short* __restrict__ ebf,
                                                      float* __restrict__ cls_part,
                                                      int* __restrict__ cnt) {
    int wave = threadIdx.x >> 6, lane = threadIdx.x & 63;
    int r = blockIdx.x * 4 + wave;

    if (blockIdx.x == 0) {
        for (int k = threadIdx.x; k < NC; k += 256) cnt[k] = 0;
    }

    {
        const float* erow = emb + (size_t)r * ND;
        float2 v = *(const float2*)(erow + lane * 2);
        unsigned int packed = (unsigned int)f2bf(v.x) | ((unsigned int)f2bf(v.y) << 16);
        *(unsigned int*)(ebf + (size_t)r * ND + lane * 2) = packed;
    }

    const float* x = logits + (size_t)r * NC;
    float4 q0 = *(const float4*)(x + 4 * lane);
    float4 q1 = *(const float4*)(x + 256 + 4 * lane);
    float4 q2 = *(const float4*)(x + 512 + 4 * lane);
    float4 q3;
    bool a3 = (192 + lane) < 250;
    if (a3) q3 = *(const float4*)(x + 768 + 4 * lane);
    else q3 = make_float4(-3.4e38f, -3.4e38f, -3.4e38f, -3.4e38f);

    float m = fmaxf(fmaxf(fmaxf(q0.x, q0.y), fmaxf(q0.z, q0.w)),
                    fmaxf(fmaxf(q1.x, q1.y), fmaxf(q1.z, q1.w)));
    m = fmaxf(m, fmaxf(fmaxf(q2.x, q2.y), fmaxf(q2.z, q2.w)));
    m = fmaxf(m, fmaxf(fmaxf(q3.x, q3.y), fmaxf(q3.z, q3.w)));
    float s = (q0.x + q0.y + q0.z + q0.w) + (q1.x + q1.y + q1.z + q1.w) +
              (q2.x + q2.y + q2.z + q2.w) +
              (a3 ? (q3.x + q3.y + q3.z + q3.w) : 0.f);
#pragma unroll
    for (int o = 32; o >= 1; o >>= 1) {
        m = fmaxf(m, __shfl_xor(m, o));
        s += __shfl_xor(s, o);
    }
    float se = expf(q0.x - m) + expf(q0.y - m) + expf(q0.z - m) + expf(q0.w - m) +
               expf(q1.x - m) + expf(q1.y - m) + expf(q1.z - m) + expf(q1.w - m) +
               expf(q2.x - m) + expf(q2.y - m) + expf(q2.z - m) + expf(q2.w - m) +
               expf(q3.x - m) + expf(q3.y - m) + expf(q3.z - m) + expf(q3.w - m);
#pragma unroll
    for (int o = 32; o >= 1; o >>= 1) se += __shfl_xor(se, o);
    float xl = x[labels[r]];
    float v = (m + logf(se)) - 0.9f * xl - 0.1f * (s * (1.0f / NC));
    if (lane == 0) cls_part[r] = v;
}

// ---------------- bucket: per-class row lists (order nondeterministic, consumers tie-break) ---
__global__ __launch_bounds__(256) void bucket_kernel(const int* __restrict__ labels,
                                                     int* __restrict__ cnt,
                                                     int* __restrict__ lists) {
    int r = blockIdx.x * 256 + threadIdx.x;
    int c = labels[r];
    int slot = atomicAdd(&cnt[c], 1);
    if (slot < CAP) lists[c * CAP + slot] = r;
}

// ---------------- mining: 8-wave blocks (16 waves/CU), j-chunked double-buffered LDS ---------
// grid (NJC, NIS) = 256 blocks x 512 threads; wave owns 64 i-rows, block sweeps 512 j.
__global__ __launch_bounds__(512, 2) void mine_kernel(const unsigned short* __restrict__ ebf,
                                                      const int* __restrict__ labels,
                                                      float* __restrict__ part) {
    __shared__ unsigned short btile[2][JBS * ND];  // 2 x 32 KB
    int tid = threadIdx.x;
    int wave = tid >> 6, lane = tid & 63;
    int col = lane & 15, grp = lane >> 4;
    int jchunk = blockIdx.x, jcbase = jchunk * (JCB * JBS);
    int ibase = blockIdx.y * 512 + wave * 64;

    // 512 threads stage 32KB in 4 issue-rounds; XOR-swizzled source, linear LDS dest (rule #21)
#define STAGE(buf, jb0)                                                                 \
    do {                                                                                \
        _Pragma("unroll")                                                               \
        for (int rep = 0; rep < 4; ++rep) {                                             \
            int row = (tid >> 4) + rep * 32;                                            \
            const unsigned short* src =                                                 \
                ebf + (size_t)((jb0) + row) * ND + (((tid & 15) ^ (row & 7)) << 3);     \
            unsigned short* dst =                                                       \
                &btile[buf][0] + (size_t)((tid >> 6) * 4 + rep * 32) * ND;              \
            __builtin_amdgcn_global_load_lds(                                           \
                (const __attribute__((address_space(1))) unsigned int*)src,             \
                (__attribute__((address_space(3))) unsigned int*)dst, 16, 0, 0);        \
        }                                                                               \
    } while (0)

    STAGE(0, jcbase);

    // A fragments: 4 i-chunks x 4 k-chunks, registers for whole kernel
    bf16x8 af[4][4];
#pragma unroll
    for (int ic = 0; ic < 4; ++ic) {
        const unsigned short* ap = ebf + (size_t)(ibase + ic * 16 + col) * ND + (grp << 3);
#pragma unroll
        for (int kc = 0; kc < 4; ++kc) af[ic][kc] = *(const bf16x8*)(ap + kc * 32);
    }
    int li[16];
#pragma unroll
    for (int ic = 0; ic < 4; ++ic)
#pragma unroll
        for (int r = 0; r < 4; ++r) li[ic * 4 + r] = labels[ibase + ic * 16 + grp * 4 + r];
    int ljall[JCB * 8];
#pragma unroll
    for (int jb = 0; jb < JCB; ++jb)
#pragma unroll
        for (int st = 0; st < 8; ++st)
            ljall[jb * 8 + st] = labels[jcbase + jb * JBS + st * 16 + col];

    float bn[16];
#pragma unroll
    for (int k = 0; k < 16; ++k) bn[k] = -3.4e38f;

    __syncthreads();  // drains stage(0) + A/label loads

#pragma unroll
    for (int t = 0; t < JCB; ++t) {
        if (t + 1 < JCB) STAGE((t + 1) & 1, jcbase + (t + 1) * JBS);

        const unsigned short* bt = &btile[t & 1][0];
#pragma unroll
        for (int st = 0; st < 8; ++st) {
            bf16x8 bfr[4];
#pragma unroll
            for (int kc = 0; kc < 4; ++kc) {
                int chunk = (grp + 4 * kc) ^ (col & 7);
                bfr[kc] = *(const bf16x8*)(bt + (size_t)(st * 16 + col) * ND + chunk * 8);
            }
            f32x4 acc[4] = {{0.f, 0.f, 0.f, 0.f}, {0.f, 0.f, 0.f, 0.f},
                            {0.f, 0.f, 0.f, 0.f}, {0.f, 0.f, 0.f, 0.f}};
#pragma unroll
            for (int kc = 0; kc < 4; ++kc)
#pragma unroll
                for (int ic = 0; ic < 4; ++ic)
                    acc[ic] = __builtin_amdgcn_mfma_f32_16x16x32_bf16(af[ic][kc], bfr[kc],
                                                                      acc[ic], 0, 0, 0);
            int lj = ljall[t * 8 + st];
#pragma unroll
            for (int ic = 0; ic < 4; ++ic)
#pragma unroll
                for (int r = 0; r < 4; ++r)
                    bn[ic * 4 + r] =
                        fmaxf(bn[ic * 4 + r], (lj == li[ic * 4 + r]) ? -3.4e38f : acc[ic][r]);
        }

        if (t + 1 < JCB) __syncthreads();
    }
#undef STAGE

#pragma unroll
    for (int k = 0; k < 16; ++k)
#pragma unroll
        for (int msk = 1; msk <= 8; msk <<= 1)
            bn[k] = fmaxf(bn[k], __shfl_xor(bn[k], msk));
    if (col == 0) {
#pragma unroll
        for (int ic = 0; ic < 4; ++ic)
#pragma unroll
            for (int r = 0; r < 4; ++r) {
                int gi = ibase + ic * 16 + grp * 4 + r;
                part[((size_t)gi << 4) + jchunk] = bn[ic * 4 + r];
            }
    }
}

// ---------------- reduce: neg from mined value; pos via parallel candidate scan --------------
// one wave per row; folds 4 rows + cls into ONE float4 per block (no atomics).
__global__ __launch_bounds__(256) void reduce_kernel(const float* __restrict__ e,
                                                     const int* __restrict__ labels,
                                                     const float* __restrict__ part,
                                                     const int* __restrict__ cnt,
                                                     const int* __restrict__ lists,
                                                     const float* __restrict__ cls_part,
                                                     float4* __restrict__ blk) {
    __shared__ float sp[4], sv[4], sc[4];
    int wave = threadIdx.x >> 6, lane = threadIdx.x & 63;
    int r = blockIdx.x * 4 + wave;
    int g = lane >> 3, sl = lane & 7;

    // merge 16 neg partials (value-only max)
    float nb = part[((size_t)r << 4) + (lane & 15)];
#pragma unroll
    for (int o = 1; o <= 8; o <<= 1) nb = fmaxf(nb, __shfl_xor(nb, o));
    float d_an = sqrtf(fmaxf(2.0f - 2.0f * nb, 0.0f));

    int myl = labels[r];
    int ctot = cnt[myl];
    int n = min(ctot, CAP);
    const float* a = e + (size_t)r * ND;

    float4 a0 = *(const float4*)(a + sl * 16);
    float4 a1 = *(const float4*)(a + sl * 16 + 4);
    float4 a2 = *(const float4*)(a + sl * 16 + 8);
    float4 a3 = *(const float4*)(a + sl * 16 + 12);

    float best = -1.0f;
    int jp = r;
    for (int base = 0; base < n; base += 8) {
        int idx = base + g;
        bool ok = (idx < n);
        int j2 = ok ? lists[myl * CAP + idx] : r;
        const float* p = e + (size_t)j2 * ND;
        float4 p0 = *(const float4*)(p + sl * 16);
        float4 p1 = *(const float4*)(p + sl * 16 + 4);
        float4 p2 = *(const float4*)(p + sl * 16 + 8);
        float4 p3 = *(const float4*)(p + sl * 16 + 12);
        float d, ss = 0.f;
        d = a0.x - p0.x; ss += d * d; d = a0.y - p0.y; ss += d * d;
        d = a0.z - p0.z; ss += d * d; d = a0.w - p0.w; ss += d * d;
        d = a1.x - p1.x; ss += d * d; d = a1.y - p1.y; ss += d * d;
        d = a1.z - p1.z; ss += d * d; d = a1.w - p1.w; ss += d * d;
        d = a2.x - p2.x; ss += d * d; d = a2.y - p2.y; ss += d * d;
        d = a2.z - p2.z; ss += d * d; d = a2.w - p2.w; ss += d * d;
        d = a3.x - p3.x; ss += d * d; d = a3.y - p3.y; ss += d * d;
        d = a3.z - p3.z; ss += d * d; d = a3.w - p3.w; ss += d * d;
        ss += __shfl_xor(ss, 1);
        ss += __shfl_xor(ss, 2);
        ss += __shfl_xor(ss, 4);  // group-uniform d2
        float d2v = (ok && j2 != r) ? ss : -2.0f;
        if (d2v > best || (d2v == best && j2 < jp)) { best = d2v; jp = j2; }
    }
#pragma unroll
    for (int msk = 8; msk <= 32; msk <<= 1) {
        float ob = __shfl_xor(best, msk);
        int oj = __shfl_xor(jp, msk);
        if (ob > best || (ob == best && oj < jp)) { best = ob; jp = oj; }
    }
    bool valid = (ctot >= 2) && (ctot < NB);

    // winner recomputed with torch's +eps inside the norm (jp==r when none: unused)
    const float* p = e + (size_t)jp * ND;
    float2 av = *(const float2*)(a + lane * 2);
    float2 pv = *(const float2*)(p + lane * 2);
    float dx = av.x - pv.x + 1e-6f, dy = av.y - pv.y + 1e-6f;
    float ss = dx * dx + dy * dy;
#pragma unroll
    for (int o = 32; o >= 1; o >>= 1) ss += __shfl_xor(ss, o);
    float d_ap = sqrtf(ss);

    if (lane == 0) {
        sp[wave] = valid ? fmaxf(d_ap - d_an + 0.5f, 0.0f) : 0.0f;
        sv[wave] = valid ? 1.0f : 0.0f;
        sc[wave] = cls_part[r];
    }
    __syncthreads();
    if (threadIdx.x == 0)
        blk[blockIdx.x] = make_float4(sp[0] + sp[1] + sp[2] + sp[3],
                                      sv[0] + sv[1] + sv[2] + sv[3],
                                      sc[0] + sc[1] + sc[2] + sc[3], 0.f);
}

// ---------------- final combine: single block tree-reduces 2048 block partials ---------------
__global__ __launch_bounds__(1024) void fin_kernel(const float4* __restrict__ blk,
                                                   float* __restrict__ out) {
    __shared__ float sc[16], sp[16], sn[16];
    int t = threadIdx.x;
    int wave = t >> 6, lane = t & 63;
    float tp = 0.f, tv = 0.f, c = 0.f;
    for (int k = t; k < NRB; k += 1024) {
        float4 q = blk[k];
        tp += q.x;
        tv += q.y;
        c += q.z;
    }
#pragma unroll
    for (int o = 32; o >= 1; o >>= 1) {
        tp += __shfl_xor(tp, o);
        tv += __shfl_xor(tv, o);
        c += __shfl_xor(c, o);
    }
    if (lane == 0) { sp[wave] = tp; sn[wave] = tv; sc[wave] = c; }
    __syncthreads();
    if (t == 0) {
        float P = 0.f, V = 0.f, C = 0.f;
        for (int w = 0; w < 16; ++w) { P += sp[w]; V += sn[w]; C += sc[w]; }
        float tri = V > 0.5f ? P / V : 0.0f;
        out[0] = C * (1.0f / NB) + tri;
    }
}

extern "C" void kernel_launch(void* const* d_in, const int* in_sizes, int n_in,
                              void* d_out, int out_size, void* d_ws, size_t ws_size,
                              hipStream_t stream) {
    const float* logits = (const float*)d_in[0];
    const float* emb = (const float*)d_in[1];
    const int* labels = (const int*)d_in[2];

    char* w = (char*)d_ws;
    unsigned short* ebf = (unsigned short*)w;                 // 2 MB
    float* part = (float*)(w + 2097152);                      // NB*16 f32 (512 KB)
    float* cls_part = (float*)(w + 2621440);                  // NB f32 (32 KB)
    int* cnt = (int*)(w + 2654208);                           // NC int (4 KB)
    int* lists = (int*)(w + 2658304);                         // NC*CAP int (256 KB)
    float4* blk = (float4*)(w + 2920448);                     // NRB float4 (32 KB)

    ce_prep_kernel<<<NB / 4, 256, 0, stream>>>(logits, emb, labels, ebf, cls_part, cnt);
    bucket_kernel<<<NB / 256, 256, 0, stream>>>(labels, cnt, lists);
    mine_kernel<<<dim3(NJC, NIS), 512, 0, stream>>>(ebf, labels, part);
    reduce_kernel<<<NRB, 256, 0, stream>>>(emb, labels, part, cnt, lists, cls_part, blk);
    fin_kernel<<<1, 1024, 0, stream>>>(blk, (float*)d_out);
}